// Round 5
// baseline (95.356 us; speedup 1.0000x reference)
//
#include <hip/hip_runtime.h>
#include <hip/hip_bf16.h>

#define NN 8192
#define DD 128
#define JTPB 16   // j-tiles (32 wide) per block

typedef __attribute__((ext_vector_type(8))) short short8;
typedef __attribute__((ext_vector_type(4))) float f32x4;

__device__ __forceinline__ unsigned short f2bf(float x) {
    unsigned u = __float_as_uint(x);
    u += 0x7FFFu + ((u >> 16) & 1u);   // round-to-nearest-even
    return (unsigned short)(u >> 16);
}
__device__ __forceinline__ float bf2f(unsigned short b) {
    return __uint_as_float(((unsigned)b) << 16);
}

__device__ __forceinline__ void gld_lds16(const float* src, float* ldst) {
    __builtin_amdgcn_global_load_lds(
        (const __attribute__((address_space(1))) void*)src,
        (__attribute__((address_space(3))) void*)ldst, 16, 0, 0);
}

// Cast emb -> bf16 (ws) and compute row sq-norms FROM THE BF16 VALUES.
__global__ void prep_kernel(const float* __restrict__ emb,
                            unsigned short* __restrict__ ebf,
                            float* __restrict__ nrm) {
    int row  = blockIdx.x * 4 + (threadIdx.x >> 6);   // 1 wave per row
    int lane = threadIdx.x & 63;
    const float2 v = *reinterpret_cast<const float2*>(emb + (size_t)row * DD + lane * 2);
    unsigned short b0 = f2bf(v.x), b1 = f2bf(v.y);
    ushort2 st; st.x = b0; st.y = b1;
    *reinterpret_cast<ushort2*>(ebf + (size_t)row * DD + lane * 2) = st;
    float f0 = bf2f(b0), f1 = bf2f(b1);
    float s = f0 * f0 + f1 * f1;
    #pragma unroll
    for (int m = 32; m; m >>= 1) s += __shfl_xor(s, m);
    if (lane == 0) nrm[row] = s;
}

// Block: 128 i-rows fixed, strides over 16 j-tiles of 32. 4 waves stacked on i
// (each wave 32i x 32j). W staged row-major -> LDS via global_load_lds
// (coalesced, chunk-XOR swizzle in 128B windows), double-buffered. 32KB LDS
// -> 4 blocks/CU so each block's vmcnt(0) drain overlaps 3 other blocks'
// streaming. Epilogue reads W^T from LDS (bank-even b128).
__global__ __launch_bounds__(256, 4)
void gram_kernel(const unsigned short* __restrict__ ebf,
                 const float* __restrict__ nrm,
                 const float* __restrict__ W,
                 float4* __restrict__ part) {
    __shared__ float wlds[2][32 * 128];   // 2 x 16 KB W tiles
    __shared__ float sw_s[4], sdw_s[4], dm_s[4];

    const int wave = threadIdx.x >> 6;
    const int lane = threadIdx.x & 63;
    const int i0  = blockIdx.y * 128;
    const int iw  = i0 + wave * 32;           // this wave's 32 i-rows
    const int jc0 = blockIdx.x * (JTPB * 32);

    const int lr = lane & 15;
    const int hi = lane >> 4;
    const int lk = hi * 8;

    // Prefetch coords: slot q = r*256 + tid -> row j'=q>>5, chunk c=q&31.
    // Source chunk = c ^ (j'&7) (involution within a 128B window).
    int pj[4], pc[4];
    #pragma unroll
    for (int r = 0; r < 4; ++r) {
        int q = r * 256 + (int)threadIdx.x;
        pj[r] = q >> 5;
        pc[r] = ((q & 31) ^ (pj[r] & 7)) * 4;
    }

    // A fragments (this wave's 32 i-rows) cached for all iterations.
    short8 af[4][2];   // [kc][m]
    #pragma unroll
    for (int kc = 0; kc < 4; ++kc)
        #pragma unroll
        for (int m = 0; m < 2; ++m)
            af[kc][m] = *reinterpret_cast<const short8*>(
                ebf + (size_t)(iw + m * 16 + lr) * DD + kc * 32 + lk);
    f32x4 ni4[2];
    #pragma unroll
    for (int m = 0; m < 2; ++m)
        ni4[m] = *reinterpret_cast<const f32x4*>(nrm + iw + m * 16 + hi * 4);

    __builtin_amdgcn_sched_barrier(0);
    // Prologue: prefetch tile 0 -> buf 0.
    #pragma unroll
    for (int r = 0; r < 4; ++r)
        gld_lds16(W + (size_t)(jc0 + pj[r]) * NN + i0 + pc[r],
                  &wlds[0][r * 1024 + wave * 256]);
    __syncthreads();

    float sW = 0.f, sDW = 0.f, dmax = 0.f;

    for (int t = 0; t < JTPB; ++t) {
        const int jw = jc0 + t * 32;
        const int cb = t & 1;

        // B fragments + col norms — issued BEFORE the prefetch so their
        // vmcnt wait (compiler, before MFMA) leaves the prefetch in flight.
        short8 bf[4][2];
        #pragma unroll
        for (int kc = 0; kc < 4; ++kc)
            #pragma unroll
            for (int n = 0; n < 2; ++n)
                bf[kc][n] = *reinterpret_cast<const short8*>(
                    ebf + (size_t)(jw + n * 16 + lr) * DD + kc * 32 + lk);
        float nj[2];
        #pragma unroll
        for (int n = 0; n < 2; ++n) nj[n] = nrm[jw + n * 16 + lr];

        __builtin_amdgcn_sched_barrier(0);
        if (t + 1 < JTPB) {
            #pragma unroll
            for (int r = 0; r < 4; ++r)
                gld_lds16(W + (size_t)(jw + 32 + pj[r]) * NN + i0 + pc[r],
                          &wlds[cb ^ 1][r * 1024 + wave * 256]);
        }
        __builtin_amdgcn_sched_barrier(0);

        // Gram MFMA: wave tile 32(i) x 32(j), K=128.
        f32x4 acc[2][2];
        #pragma unroll
        for (int m = 0; m < 2; ++m)
            #pragma unroll
            for (int n = 0; n < 2; ++n) acc[m][n] = (f32x4){0.f, 0.f, 0.f, 0.f};
        #pragma unroll
        for (int kc = 0; kc < 4; ++kc)
            #pragma unroll
            for (int m = 0; m < 2; ++m)
                #pragma unroll
                for (int n = 0; n < 2; ++n)
                    acc[m][n] = __builtin_amdgcn_mfma_f32_16x16x32_bf16(
                        af[kc][m], bf[kc][n], acc[m][n], 0, 0, 0);

        // Epilogue: W^T from LDS (swizzled), dist, accumulate.
        #pragma unroll
        for (int m = 0; m < 2; ++m) {
            #pragma unroll
            for (int n = 0; n < 2; ++n) {
                const int jp = n * 16 + lr;
                const int ck = (wave * 8 + m * 4 + hi) ^ (jp & 7);
                const f32x4 w4 = *reinterpret_cast<const f32x4*>(
                    &wlds[cb][jp * 128 + ck * 4]);
                #pragma unroll
                for (int r = 0; r < 4; ++r) {
                    float sq = ni4[m][r] + nj[n] - 2.0f * acc[m][n][r];
                    sq = fmaxf(sq, 0.0f);
                    float d = sqrtf(sq);
                    sW  += w4[r];
                    sDW += w4[r] * d;
                    dmax = fmaxf(dmax, d);
                }
            }
        }
        // Drains this wave's prefetch + barrier: buf cb^1 ready for iter t+1,
        // and everyone is done reading buf cb before iter t+1 overwrites it.
        __syncthreads();
    }

    #pragma unroll
    for (int m = 32; m; m >>= 1) {
        sW  += __shfl_xor(sW, m);
        sDW += __shfl_xor(sDW, m);
        dmax = fmaxf(dmax, __shfl_xor(dmax, m));
    }
    if (lane == 0) { sw_s[wave] = sW; sdw_s[wave] = sDW; dm_s[wave] = dmax; }
    __syncthreads();
    if (threadIdx.x == 0) {
        float SW = 0.f, SDW = 0.f, DM = 0.f;
        #pragma unroll
        for (int k = 0; k < 4; ++k) {
            SW += sw_s[k]; SDW += sdw_s[k]; DM = fmaxf(DM, dm_s[k]);
        }
        float4 p; p.x = SW; p.y = SDW; p.z = DM; p.w = 0.f;
        part[blockIdx.y * gridDim.x + blockIdx.x] = p;
    }
}

// Single block: reduce per-block partials in fp64, emit the loss.
__global__ __launch_bounds__(512)
void reduce_kernel(const float4* __restrict__ part, int nblk,
                   float* __restrict__ out) {
    const int tid = threadIdx.x;
    double sW = 0.0, sDW = 0.0;
    float dmax = 0.f;
    for (int idx = tid; idx < nblk; idx += 512) {
        float4 p = part[idx];
        sW += (double)p.x; sDW += (double)p.y; dmax = fmaxf(dmax, p.z);
    }
    #pragma unroll
    for (int m = 32; m; m >>= 1) {
        sW  += __shfl_xor(sW, m);
        sDW += __shfl_xor(sDW, m);
        dmax = fmaxf(dmax, __shfl_xor(dmax, m));
    }
    __shared__ double sw_s[8], sdw_s[8];
    __shared__ float dm_s[8];
    const int w = tid >> 6, l = tid & 63;
    if (l == 0) { sw_s[w] = sW; sdw_s[w] = sDW; dm_s[w] = dmax; }
    __syncthreads();
    if (tid == 0) {
        double SW = 0.0, SDW = 0.0; float DM = 0.f;
        #pragma unroll
        for (int k = 0; k < 8; ++k) {
            SW += sw_s[k]; SDW += sdw_s[k]; DM = fmaxf(DM, dm_s[k]);
        }
        out[0] = (float)((SW - SDW / (double)DM) / ((double)NN * (double)NN));
    }
}

extern "C" void kernel_launch(void* const* d_in, const int* in_sizes, int n_in,
                              void* d_out, int out_size, void* d_ws, size_t ws_size,
                              hipStream_t stream) {
    const float* emb = (const float*)d_in[0];
    const float* W   = (const float*)d_in[1];
    float* out = (float*)d_out;

    char* ws = (char*)d_ws;
    float4* part        = (float4*)ws;                               // 16 KB (1024 x 16B)
    unsigned short* ebf = (unsigned short*)(ws + 32768);             // 2 MB bf16 emb
    float* nrm          = (float*)(ws + 32768 + (size_t)NN * DD * 2);// 32 KB norms

    prep_kernel<<<NN / 4, 256, 0, stream>>>(emb, ebf, nrm);
    dim3 grid(NN / (32 * JTPB), NN / 128);   // 16 x 64 = 1024 blocks (4/CU)
    gram_kernel<<<grid, 256, 0, stream>>>(ebf, nrm, W, part);
    reduce_kernel<<<1, 512, 0, stream>>>(part, grid.x * grid.y, out);
}

// Round 6
// 89.267 us; speedup vs baseline: 1.0682x; 1.0682x over previous
//
#include <hip/hip_runtime.h>
#include <hip/hip_bf16.h>

#define NN 8192
#define DD 128
#define JT 16          // j-tiles per wave
#define JR 16          // j-rows per tile

typedef __attribute__((ext_vector_type(8))) short short8;
typedef __attribute__((ext_vector_type(4))) float f32x4;

__device__ __forceinline__ unsigned short f2bf(float x) {
    unsigned u = __float_as_uint(x);
    u += 0x7FFFu + ((u >> 16) & 1u);   // round-to-nearest-even
    return (unsigned short)(u >> 16);
}
__device__ __forceinline__ float bf2f(unsigned short b) {
    return __uint_as_float(((unsigned)b) << 16);
}

__device__ __forceinline__ void gld_lds16(const float* src, float* ldst) {
    __builtin_amdgcn_global_load_lds(
        (const __attribute__((address_space(1))) void*)src,
        (__attribute__((address_space(3))) void*)ldst, 16, 0, 0);
}

// Cast emb -> bf16 (ws) and compute row sq-norms FROM THE BF16 VALUES.
__global__ void prep_kernel(const float* __restrict__ emb,
                            unsigned short* __restrict__ ebf,
                            float* __restrict__ nrm) {
    int row  = blockIdx.x * 4 + (threadIdx.x >> 6);   // 1 wave per row
    int lane = threadIdx.x & 63;
    const float2 v = *reinterpret_cast<const float2*>(emb + (size_t)row * DD + lane * 2);
    unsigned short b0 = f2bf(v.x), b1 = f2bf(v.y);
    ushort2 st; st.x = b0; st.y = b1;
    *reinterpret_cast<ushort2*>(ebf + (size_t)row * DD + lane * 2) = st;
    float f0 = bf2f(b0), f1 = bf2f(b1);
    float s = f0 * f0 + f1 * f1;
    #pragma unroll
    for (int m = 32; m; m >>= 1) s += __shfl_xor(s, m);
    if (lane == 0) nrm[row] = s;
}

// Wave-private streaming: each wave owns 32 i-cols x 256 j-rows (16 tiles of
// 16 j). W tiles staged into the wave's OWN LDS slab (ring-3) via
// global_load_lds with pre-swizzled source; NO __syncthreads in the loop --
// counted s_waitcnt vmcnt(2) keeps the next tile's loads in flight forever.
// bf fragments prefetched 1 tile ahead (issued BEFORE the stage so the
// vmcnt count is exact). Epilogue reads W^T from LDS at the b128 bank floor.
__global__ __launch_bounds__(256, 3)
void gram_kernel(const unsigned short* __restrict__ ebf,
                 const float* __restrict__ nrm,
                 const float* __restrict__ W,
                 float4* __restrict__ part) {
    __shared__ float wlds[4][3][JR * 32];   // 4 waves x ring3 x 2KB tiles
    __shared__ float sw_s[4], sdw_s[4], dm_s[4];

    const int wave = threadIdx.x >> 6;
    const int lane = threadIdx.x & 63;
    const int lr = lane & 15;
    const int hi = lane >> 4;

    const int i0w = blockIdx.x * 128 + wave * 32;   // wave's 32 i-cols
    const int j0  = blockIdx.y * 256;               // wave's 256 j-rows

    // Stage source coords: instr q stages LDS rows q*8+(l>>3), chunk c=l&7;
    // source chunk pre-swizzled: cs = c ^ (row&7)  (involution per row).
    const int srow = lane >> 3;                     // 0..7
    const int schk = (lane & 7) ^ srow;
    const float* wsrc = W + (size_t)(j0 + srow) * NN + i0w + schk * 4;

    // A fragments (wave's 32 i-rows) + row norms, cached for all 16 tiles.
    short8 af[4][2];
    #pragma unroll
    for (int kc = 0; kc < 4; ++kc)
        #pragma unroll
        for (int m = 0; m < 2; ++m)
            af[kc][m] = *reinterpret_cast<const short8*>(
                ebf + (size_t)(i0w + m * 16 + lr) * DD + kc * 32 + hi * 8);
    f32x4 ni4[2];
    #pragma unroll
    for (int m = 0; m < 2; ++m)
        ni4[m] = *reinterpret_cast<const f32x4*>(nrm + i0w + m * 16 + hi * 4);

    auto stage = [&](int t, int buf) {
        float* dst = &wlds[wave][buf][0];
        const float* s = wsrc + (size_t)t * JR * NN;
        gld_lds16(s, dst);
        gld_lds16(s + 8 * NN, dst + 256);
    };
    auto loadbf = [&](int t, short8 (&bf)[4], float& nj) {
        const int jr = j0 + t * JR + lr;
        #pragma unroll
        for (int kc = 0; kc < 4; ++kc)
            bf[kc] = *reinterpret_cast<const short8*>(
                ebf + (size_t)jr * DD + kc * 32 + hi * 8);
        nj = nrm[jr];
    };

    short8 bfA[4], bfB[4];
    float njA = 0.f, njB = 0.f;
    float sW = 0.f, sDW = 0.f, dmax = 0.f;

    // Prologue. Issue order matters for vmcnt counting:
    // [stage(0):2][bf(0):5][stage(1):2] -> wait vmcnt(2) leaves stage(1).
    stage(0, 0);
    __builtin_amdgcn_sched_barrier(0);
    loadbf(0, bfA, njA);
    __builtin_amdgcn_sched_barrier(0);
    stage(1, 1);
    __builtin_amdgcn_sched_barrier(0);

    auto doTile = [&](int t, short8 (&bfc)[4], float& njc,
                      short8 (&bfn)[4], float& njn) {
        // Wait for stage(t)+bf(t); keep stage(t+1)'s 2 loads in flight.
        if (t < JT - 1) asm volatile("s_waitcnt vmcnt(2)" ::: "memory");
        else            asm volatile("s_waitcnt vmcnt(0)" ::: "memory");
        __builtin_amdgcn_sched_barrier(0);

        // W^T from this wave's LDS (swizzle -> 8 lanes/bank-quad = b128 floor)
        const float* lb = &wlds[wave][t % 3][0];
        f32x4 w4[2];
        #pragma unroll
        for (int m = 0; m < 2; ++m)
            w4[m] = *reinterpret_cast<const f32x4*>(
                lb + lr * 32 + (((m * 4 + hi) ^ (lr & 7)) * 4));
        __builtin_amdgcn_sched_barrier(0);

        // Gram MFMA: 32i x 16j, K=128.
        f32x4 acc[2] = {(f32x4){0.f,0.f,0.f,0.f}, (f32x4){0.f,0.f,0.f,0.f}};
        #pragma unroll
        for (int kc = 0; kc < 4; ++kc)
            #pragma unroll
            for (int m = 0; m < 2; ++m)
                acc[m] = __builtin_amdgcn_mfma_f32_16x16x32_bf16(
                    af[kc][m], bfc[kc], acc[m], 0, 0, 0);

        // Prefetch next bf BEFORE next stage (keeps vmcnt counts exact).
        if (t + 1 < JT) loadbf(t + 1, bfn, njn);
        __builtin_amdgcn_sched_barrier(0);
        if (t + 2 < JT) stage(t + 2, (t + 2) % 3);
        __builtin_amdgcn_sched_barrier(0);

        // Epilogue: dist = sqrt(max(0, ni + nj - 2*dot)), pair with W^T.
        #pragma unroll
        for (int m = 0; m < 2; ++m)
            #pragma unroll
            for (int r = 0; r < 4; ++r) {
                float sq = ni4[m][r] + njc - 2.0f * acc[m][r];
                float d = sqrtf(fmaxf(sq, 0.0f));
                sW  += w4[m][r];
                sDW += w4[m][r] * d;
                dmax = fmaxf(dmax, d);
            }
    };

    #pragma unroll
    for (int t = 0; t < JT; t += 2) {
        doTile(t,     bfA, njA, bfB, njB);
        doTile(t + 1, bfB, njB, bfA, njA);
    }

    #pragma unroll
    for (int m = 32; m; m >>= 1) {
        sW  += __shfl_xor(sW, m);
        sDW += __shfl_xor(sDW, m);
        dmax = fmaxf(dmax, __shfl_xor(dmax, m));
    }
    if (lane == 0) { sw_s[wave] = sW; sdw_s[wave] = sDW; dm_s[wave] = dmax; }
    __syncthreads();
    if (threadIdx.x == 0) {
        float SW = 0.f, SDW = 0.f, DM = 0.f;
        #pragma unroll
        for (int k = 0; k < 4; ++k) {
            SW += sw_s[k]; SDW += sdw_s[k]; DM = fmaxf(DM, dm_s[k]);
        }
        float4 p; p.x = SW; p.y = SDW; p.z = DM; p.w = 0.f;
        part[blockIdx.y * gridDim.x + blockIdx.x] = p;
    }
}

// Single block: reduce per-block partials in fp64, emit the loss.
__global__ __launch_bounds__(512)
void reduce_kernel(const float4* __restrict__ part, int nblk,
                   float* __restrict__ out) {
    const int tid = threadIdx.x;
    double sW = 0.0, sDW = 0.0;
    float dmax = 0.f;
    for (int idx = tid; idx < nblk; idx += 512) {
        float4 p = part[idx];
        sW += (double)p.x; sDW += (double)p.y; dmax = fmaxf(dmax, p.z);
    }
    #pragma unroll
    for (int m = 32; m; m >>= 1) {
        sW  += __shfl_xor(sW, m);
        sDW += __shfl_xor(sDW, m);
        dmax = fmaxf(dmax, __shfl_xor(dmax, m));
    }
    __shared__ double sw_s[8], sdw_s[8];
    __shared__ float dm_s[8];
    const int w = tid >> 6, l = tid & 63;
    if (l == 0) { sw_s[w] = sW; sdw_s[w] = sDW; dm_s[w] = dmax; }
    __syncthreads();
    if (tid == 0) {
        double SW = 0.0, SDW = 0.0; float DM = 0.f;
        #pragma unroll
        for (int k = 0; k < 8; ++k) {
            SW += sw_s[k]; SDW += sdw_s[k]; DM = fmaxf(DM, dm_s[k]);
        }
        out[0] = (float)((SW - SDW / (double)DM) / ((double)NN * (double)NN));
    }
}

extern "C" void kernel_launch(void* const* d_in, const int* in_sizes, int n_in,
                              void* d_out, int out_size, void* d_ws, size_t ws_size,
                              hipStream_t stream) {
    const float* emb = (const float*)d_in[0];
    const float* W   = (const float*)d_in[1];
    float* out = (float*)d_out;

    char* ws = (char*)d_ws;
    float4* part        = (float4*)ws;                               // 32 KB (2048 x 16B)
    unsigned short* ebf = (unsigned short*)(ws + 65536);             // 2 MB bf16 emb
    float* nrm          = (float*)(ws + 65536 + (size_t)NN * DD * 2);// 32 KB norms

    prep_kernel<<<NN / 4, 256, 0, stream>>>(emb, ebf, nrm);
    dim3 grid(NN / 128, NN / 256);   // 64 x 32 = 2048 blocks
    gram_kernel<<<grid, 256, 0, stream>>>(ebf, nrm, W, part);
    reduce_kernel<<<1, 512, 0, stream>>>(part, grid.x * grid.y, out);
}

// Round 8
// 85.228 us; speedup vs baseline: 1.1188x; 1.0474x over previous
//
#include <hip/hip_runtime.h>
#include <hip/hip_bf16.h>

#define NN 8192
#define DD 128
#define JT 64          // 16-row j-tiles per wave (1024 j-rows per block)

typedef __attribute__((ext_vector_type(8))) short short8;
typedef __attribute__((ext_vector_type(4))) float f32x4;
typedef __attribute__((address_space(3))) float lds_f;

__device__ __forceinline__ unsigned short f2bf(float x) {
    unsigned u = __float_as_uint(x);
    u += 0x7FFFu + ((u >> 16) & 1u);   // round-to-nearest-even
    return (unsigned short)(u >> 16);
}
__device__ __forceinline__ float bf2f(unsigned short b) {
    return __uint_as_float(((unsigned)b) << 16);
}

__device__ __forceinline__ void gld_lds16(const float* src, float* ldst) {
    __builtin_amdgcn_global_load_lds(
        (const __attribute__((address_space(1))) void*)src,
        (__attribute__((address_space(3))) void*)ldst, 16, 0, 0);
}

// Cast emb -> bf16 (ws) and compute row sq-norms FROM THE BF16 VALUES.
__global__ void prep_kernel(const float* __restrict__ emb,
                            unsigned short* __restrict__ ebf,
                            float* __restrict__ nrm) {
    int row  = blockIdx.x * 4 + (threadIdx.x >> 6);   // 1 wave per row
    int lane = threadIdx.x & 63;
    const float2 v = *reinterpret_cast<const float2*>(emb + (size_t)row * DD + lane * 2);
    unsigned short b0 = f2bf(v.x), b1 = f2bf(v.y);
    ushort2 st; st.x = b0; st.y = b1;
    *reinterpret_cast<ushort2*>(ebf + (size_t)row * DD + lane * 2) = st;
    float f0 = bf2f(b0), f1 = bf2f(b1);
    float s = f0 * f0 + f1 * f1;
    #pragma unroll
    for (int m = 32; m; m >>= 1) s += __shfl_xor(s, m);
    if (lane == 0) nrm[row] = s;
}

// --- per-tile body -------------------------------------------------------
// Queue invariant at wait: [pair(t):7, pair(t+1):7, pair(t+2):7] -> vmcnt(14)
// retires pair(t) (bf regs + this tile's LDS W data). Inline-asm ds_read of
// W^T (so the compiler can't insert its own conservative drains), then issue
// pair(t+3) (bf BEFORE stage keeps the in-order counter clean), then MFMA,
// then lgkmcnt(0)+epilogue.
#define DO_TILE(NSTR, ISSUE, OFFS, SOFF, bfc, njc, bff, njf)                   \
  {                                                                            \
    asm volatile("s_waitcnt vmcnt(" NSTR ")" ::: "memory");                    \
    __builtin_amdgcn_sched_barrier(0);                                         \
    f32x4 w40, w41;                                                            \
    asm volatile("ds_read_b128 %0, %2 offset:" OFFS "\n\t"                     \
                 "ds_read_b128 %1, %3 offset:" OFFS                            \
                 : "=&v"(w40), "=&v"(w41)                                      \
                 : "v"(lp0), "v"(lp1));                                        \
    __builtin_amdgcn_sched_barrier(0);                                         \
    if (ISSUE) {                                                               \
      bff[0] = *reinterpret_cast<const short8*>(ebnext);                       \
      bff[1] = *reinterpret_cast<const short8*>(ebnext + 32);                  \
      bff[2] = *reinterpret_cast<const short8*>(ebnext + 64);                  \
      bff[3] = *reinterpret_cast<const short8*>(ebnext + 96);                  \
      njf = *njnext;                                                           \
      __builtin_amdgcn_sched_barrier(0);                                       \
      gld_lds16(wnext,          sbase + (SOFF));                               \
      gld_lds16(wnext + 8 * NN, sbase + (SOFF) + 256);                         \
      ebnext += 16 * DD; njnext += 16; wnext += (size_t)16 * NN;               \
    }                                                                          \
    __builtin_amdgcn_sched_barrier(0);                                         \
    f32x4 a0 = {0.f,0.f,0.f,0.f}, a1 = {0.f,0.f,0.f,0.f};                      \
    a0 = __builtin_amdgcn_mfma_f32_16x16x32_bf16(af[0][0], bfc[0], a0,0,0,0);  \
    a1 = __builtin_amdgcn_mfma_f32_16x16x32_bf16(af[0][1], bfc[0], a1,0,0,0);  \
    a0 = __builtin_amdgcn_mfma_f32_16x16x32_bf16(af[1][0], bfc[1], a0,0,0,0);  \
    a1 = __builtin_amdgcn_mfma_f32_16x16x32_bf16(af[1][1], bfc[1], a1,0,0,0);  \
    a0 = __builtin_amdgcn_mfma_f32_16x16x32_bf16(af[2][0], bfc[2], a0,0,0,0);  \
    a1 = __builtin_amdgcn_mfma_f32_16x16x32_bf16(af[2][1], bfc[2], a1,0,0,0);  \
    a0 = __builtin_amdgcn_mfma_f32_16x16x32_bf16(af[3][0], bfc[3], a0,0,0,0);  \
    a1 = __builtin_amdgcn_mfma_f32_16x16x32_bf16(af[3][1], bfc[3], a1,0,0,0);  \
    asm volatile("s_waitcnt lgkmcnt(0)" ::: "memory");                         \
    __builtin_amdgcn_sched_barrier(0);                                         \
    for (int r = 0; r < 4; ++r) {                                              \
      float sq = ni4[0][r] + (njc) - 2.0f * a0[r];                             \
      float d  = sqrtf(fmaxf(sq, 0.0f));                                       \
      sW += w40[r]; sDW += w40[r] * d; dmax = fmaxf(dmax, d);                  \
    }                                                                          \
    for (int r = 0; r < 4; ++r) {                                              \
      float sq = ni4[1][r] + (njc) - 2.0f * a1[r];                             \
      float d  = sqrtf(fmaxf(sq, 0.0f));                                       \
      sW += w41[r]; sDW += w41[r] * d; dmax = fmaxf(dmax, d);                  \
    }                                                                          \
  }

#define PRO_PAIR(bff, njf, SOFF)                                               \
  {                                                                            \
    bff[0] = *reinterpret_cast<const short8*>(ebnext);                         \
    bff[1] = *reinterpret_cast<const short8*>(ebnext + 32);                    \
    bff[2] = *reinterpret_cast<const short8*>(ebnext + 64);                    \
    bff[3] = *reinterpret_cast<const short8*>(ebnext + 96);                    \
    njf = *njnext;                                                             \
    __builtin_amdgcn_sched_barrier(0);                                         \
    gld_lds16(wnext,          sbase + (SOFF));                                 \
    gld_lds16(wnext + 8 * NN, sbase + (SOFF) + 256);                           \
    ebnext += 16 * DD; njnext += 16; wnext += (size_t)16 * NN;                 \
    __builtin_amdgcn_sched_barrier(0);                                         \
  }

// Wave-private streaming gram: each wave owns 32 i-cols x 1024 j-rows, split
// into 64 tiles of 16 j. W tiles (2KB) staged into the wave's own ring-4 LDS
// slab via global_load_lds (full 128B-line requests, chunk-XOR pre-swizzle).
// 3-deep pipeline, zero barriers, counted vmcnt(14). ds_read via inline asm.
__global__ __launch_bounds__(256, 2)
void gram_kernel(const unsigned short* __restrict__ ebf,
                 const float* __restrict__ nrm,
                 const float* __restrict__ W,
                 float4* __restrict__ part) {
    __shared__ float wlds[4][4][16 * 32];   // wave x ring4 x 2KB
    __shared__ float sw_s[4], sdw_s[4], dm_s[4];

    const int wave = threadIdx.x >> 6;
    const int lane = threadIdx.x & 63;
    const int lr = lane & 15;
    const int hi = lane >> 4;

    const int i0w = blockIdx.x * 128 + wave * 32;   // wave's 32 i-cols
    const int j0  = blockIdx.y * (JT * 16);         // wave's 1024 j-rows

    // Stage lane coords: lane l covers row srow (of 8 per instr), 16B chunk
    // schk pre-swizzled by the row (involution within the 128B row).
    const int srow = lane >> 3;                 // 0..7
    const int schk = (lane & 7) ^ srow;         // source chunk (swizzled)

    // Running source pointers. NOTE: ebnext includes the per-lane k-offset
    // hi*8 (R7 bug: it was missing -> wrong B fragments in lanes 16..63).
    const float* wnext = W + (size_t)(j0 + srow) * NN + i0w + schk * 4;
    const unsigned short* ebnext = ebf + (size_t)(j0 + lr) * DD + hi * 8;
    const float* njnext = nrm + j0 + lr;

    // LDS bases: stage base (wave-uniform) + per-lane read pointers.
    float* sbase = &wlds[wave][0][0];
    const int chunk0 = hi ^ (lr & 7);           // m=0 logical chunks 0..3
    const int chunk1 = (4 + hi) ^ (lr & 7);     // m=1 logical chunks 4..7
    const lds_f* lp0 = (const lds_f*)(sbase + lr * 32 + chunk0 * 4);
    const lds_f* lp1 = (const lds_f*)(sbase + lr * 32 + chunk1 * 4);

    // A fragments (wave's 32 i-rows) + row norms, cached for all tiles.
    short8 af[4][2];
    #pragma unroll
    for (int kc = 0; kc < 4; ++kc)
        #pragma unroll
        for (int m = 0; m < 2; ++m)
            af[kc][m] = *reinterpret_cast<const short8*>(
                ebf + (size_t)(i0w + m * 16 + lr) * DD + kc * 32 + hi * 8);
    f32x4 ni4[2];
    #pragma unroll
    for (int m = 0; m < 2; ++m)
        ni4[m] = *reinterpret_cast<const f32x4*>(nrm + i0w + m * 16 + hi * 4);
    __builtin_amdgcn_sched_barrier(0);

    short8 bfA[4], bfB[4], bfC[4], bfD[4];
    float njA = 0.f, njB = 0.f, njC = 0.f, njD = 0.f;
    float sW = 0.f, sDW = 0.f, dmax = 0.f;

    // Prologue: pairs 0,1,2 -> bufs 0,1,2 (queue = 21 vm ops + 10 A/ni ops;
    // the first vmcnt(14) retires the A/ni loads AND pair 0 exactly).
    PRO_PAIR(bfA, njA, 0);
    PRO_PAIR(bfB, njB, 512);
    PRO_PAIR(bfC, njC, 1024);

    // Main loop: t = 0..59 (15 x 4), all steady-state vmcnt(14), issue t+3.
    for (int t4 = 0; t4 < JT - 4; t4 += 4) {
        DO_TILE("14", 1, "0",    1536, bfA, njA, bfD, njD);  // t%4==0
        DO_TILE("14", 1, "2048", 0,    bfB, njB, bfA, njA);  // t%4==1
        DO_TILE("14", 1, "4096", 512,  bfC, njC, bfB, njB);  // t%4==2
        DO_TILE("14", 1, "6144", 1024, bfD, njD, bfC, njC);  // t%4==3
    }
    // Peel t = 60..63 (last issue at t=60 fills pair 63).
    DO_TILE("14", 1, "0",    1536, bfA, njA, bfD, njD);      // t=60
    DO_TILE("14", 0, "2048", 0,    bfB, njB, bfA, njA);      // t=61
    DO_TILE("7",  0, "4096", 0,    bfC, njC, bfA, njA);      // t=62
    DO_TILE("0",  0, "6144", 0,    bfD, njD, bfA, njA);      // t=63

    #pragma unroll
    for (int m = 32; m; m >>= 1) {
        sW  += __shfl_xor(sW, m);
        sDW += __shfl_xor(sDW, m);
        dmax = fmaxf(dmax, __shfl_xor(dmax, m));
    }
    if (lane == 0) { sw_s[wave] = sW; sdw_s[wave] = sDW; dm_s[wave] = dmax; }
    __syncthreads();
    if (threadIdx.x == 0) {
        float SW = 0.f, SDW = 0.f, DM = 0.f;
        #pragma unroll
        for (int k = 0; k < 4; ++k) {
            SW += sw_s[k]; SDW += sdw_s[k]; DM = fmaxf(DM, dm_s[k]);
        }
        float4 p; p.x = SW; p.y = SDW; p.z = DM; p.w = 0.f;
        part[blockIdx.y * gridDim.x + blockIdx.x] = p;
    }
}

// Single block: reduce per-block partials in fp64, emit the loss.
__global__ __launch_bounds__(512)
void reduce_kernel(const float4* __restrict__ part, int nblk,
                   float* __restrict__ out) {
    const int tid = threadIdx.x;
    double sW = 0.0, sDW = 0.0;
    float dmax = 0.f;
    for (int idx = tid; idx < nblk; idx += 512) {
        float4 p = part[idx];
        sW += (double)p.x; sDW += (double)p.y; dmax = fmaxf(dmax, p.z);
    }
    #pragma unroll
    for (int m = 32; m; m >>= 1) {
        sW  += __shfl_xor(sW, m);
        sDW += __shfl_xor(sDW, m);
        dmax = fmaxf(dmax, __shfl_xor(dmax, m));
    }
    __shared__ double sw_s[8], sdw_s[8];
    __shared__ float dm_s[8];
    const int w = tid >> 6, l = tid & 63;
    if (l == 0) { sw_s[w] = sW; sdw_s[w] = sDW; dm_s[w] = dmax; }
    __syncthreads();
    if (tid == 0) {
        double SW = 0.0, SDW = 0.0; float DM = 0.f;
        #pragma unroll
        for (int k = 0; k < 8; ++k) {
            SW += sw_s[k]; SDW += sdw_s[k]; DM = fmaxf(DM, dm_s[k]);
        }
        out[0] = (float)((SW - SDW / (double)DM) / ((double)NN * (double)NN));
    }
}

extern "C" void kernel_launch(void* const* d_in, const int* in_sizes, int n_in,
                              void* d_out, int out_size, void* d_ws, size_t ws_size,
                              hipStream_t stream) {
    const float* emb = (const float*)d_in[0];
    const float* W   = (const float*)d_in[1];
    float* out = (float*)d_out;

    char* ws = (char*)d_ws;
    float4* part        = (float4*)ws;                               // 8 KB (512 x 16B)
    unsigned short* ebf = (unsigned short*)(ws + 16384);             // 2 MB bf16 emb
    float* nrm          = (float*)(ws + 16384 + (size_t)NN * DD * 2);// 32 KB norms

    prep_kernel<<<NN / 4, 256, 0, stream>>>(emb, ebf, nrm);
    dim3 grid(NN / 128, NN / (JT * 16));   // 64 x 8 = 512 blocks (2/CU exact)
    gram_kernel<<<grid, 256, 0, stream>>>(ebf, nrm, W, part);
    reduce_kernel<<<1, 512, 0, stream>>>(part, grid.x * grid.y, out);
}